// Round 1
// baseline (1299.878 us; speedup 1.0000x reference)
//
#include <hip/hip_runtime.h>

// out[b,g] = sum_l x[b,g,l] * W[l,g] + bias[g]
// x: (8192, 8, 4096) fp32, W: (1, 4096, 8) fp32, bias: (8,) fp32 -> out (8192, 8) fp32
// Memory-bound: 1.074 GB of x read once. One wave per (b,g) row.

constexpr int Bsz = 8192;
constexpr int G   = 8;
constexpr int L   = 4096;

// Transpose weight (L,G) -> (G,L) so the main kernel reads it with coalesced float4.
__global__ __launch_bounds__(256) void transpose_w_kernel(const float* __restrict__ w,
                                                          float* __restrict__ wt) {
    int idx = blockIdx.x * 256 + threadIdx.x;   // over L*G = 32768
    if (idx < L * G) {
        int l = idx >> 3;       // idx / G
        int g = idx & (G - 1);  // idx % G
        wt[g * L + l] = w[idx];
    }
}

template <bool TRANSPOSED>
__global__ __launch_bounds__(256) void gfc_kernel(const float* __restrict__ x,
                                                  const float* __restrict__ w,
                                                  const float* __restrict__ bias,
                                                  float* __restrict__ out) {
    const int wid  = threadIdx.x >> 6;            // wave in block: 0..3
    const int lane = threadIdx.x & 63;
    const int row  = blockIdx.x * 4 + wid;        // 0 .. B*G-1 (one wave per row)
    const int g    = row & (G - 1);

    const float4* __restrict__ xr =
        reinterpret_cast<const float4*>(x) + (size_t)row * (L / 4);

    float acc[4] = {0.f, 0.f, 0.f, 0.f};

    if (TRANSPOSED) {
        const float4* __restrict__ wr =
            reinterpret_cast<const float4*>(w) + (size_t)g * (L / 4);
#pragma unroll
        for (int it = 0; it < 16; ++it) {
            float4 xv = xr[it * 64 + lane];
            float4 wv = wr[it * 64 + lane];
            float a = acc[it & 3];
            a = fmaf(xv.x, wv.x, a);
            a = fmaf(xv.y, wv.y, a);
            a = fmaf(xv.z, wv.z, a);
            a = fmaf(xv.w, wv.w, a);
            acc[it & 3] = a;
        }
    } else {
        // Fallback: strided weight reads straight from L2 (weight is 128 KiB, cache-hot).
#pragma unroll
        for (int it = 0; it < 16; ++it) {
            float4 xv = xr[it * 64 + lane];
            int l = (it * 64 + lane) * 4;
            float a = acc[it & 3];
            a = fmaf(xv.x, w[(l + 0) * G + g], a);
            a = fmaf(xv.y, w[(l + 1) * G + g], a);
            a = fmaf(xv.z, w[(l + 2) * G + g], a);
            a = fmaf(xv.w, w[(l + 3) * G + g], a);
            acc[it & 3] = a;
        }
    }

    float acc_s = (acc[0] + acc[1]) + (acc[2] + acc[3]);

    // 64-lane wave reduction
#pragma unroll
    for (int off = 32; off > 0; off >>= 1)
        acc_s += __shfl_down(acc_s, off, 64);

    if (lane == 0)
        out[row] = acc_s + bias[g];
}

extern "C" void kernel_launch(void* const* d_in, const int* in_sizes, int n_in,
                              void* d_out, int out_size, void* d_ws, size_t ws_size,
                              hipStream_t stream) {
    const float* x    = (const float*)d_in[0];
    const float* w    = (const float*)d_in[1];
    const float* bias = (const float*)d_in[2];
    float* out        = (float*)d_out;

    const int num_rows   = Bsz * G;        // 65536
    const int num_blocks = num_rows / 4;   // 4 waves (rows) per 256-thread block

    if (ws_size >= (size_t)(L * G) * sizeof(float)) {
        float* wt = (float*)d_ws;
        transpose_w_kernel<<<(L * G + 255) / 256, 256, 0, stream>>>(w, wt);
        gfc_kernel<true><<<num_blocks, 256, 0, stream>>>(x, wt, bias, out);
    } else {
        gfc_kernel<false><<<num_blocks, 256, 0, stream>>>(x, w, bias, out);
    }
}